// Round 3
// baseline (2608.806 us; speedup 1.0000x reference)
//
#include <hip/hip_runtime.h>

#define NF_ATOM 9
#define NF_BOND 3
#define DD 128
#define HH 256
#define NLAYER 5

typedef float fv4 __attribute__((ext_vector_type(4)));
typedef __bf16 bfv8 __attribute__((ext_vector_type(8)));
typedef unsigned int uv4 __attribute__((ext_vector_type(4)));

__device__ inline unsigned short f2bf(float f) {
    unsigned int u = __builtin_bit_cast(unsigned int, f);
    u = u + 0x7FFFu + ((u >> 16) & 1u);
    return (unsigned short)(u >> 16);
}
__device__ inline float bf2f(unsigned short s) {
    unsigned int u = ((unsigned int)s) << 16;
    return __builtin_bit_cast(float, u);
}

// ---------- atom encoder: h0 (f32) into y2 buffer ----------
__global__ __launch_bounds__(256) void k_atom(const int* __restrict__ x,
        const float* __restrict__ emb, float* __restrict__ h, int N) {
    int gid = blockIdx.x * 256 + threadIdx.x;
    int n = gid >> 5;
    if (n >= N) return;
    int c = (gid & 31) << 2;
    const int* xr = x + n * NF_ATOM;
    float4 acc = make_float4(0.f, 0.f, 0.f, 0.f);
#pragma unroll
    for (int f = 0; f < NF_ATOM; ++f) {
        int idx = xr[f];
        float4 v = *(const float4*)(emb + ((size_t)(f * 120 + idx) * DD) + c);
        acc.x += v.x; acc.y += v.y; acc.z += v.z; acc.w += v.w;
    }
    *(float4*)(h + (size_t)n * DD + c) = acc;
}

// ---------- weight convert: f32 [K][N] -> bf16 chunk-major [l][kc][n][32k] ----------
__global__ __launch_bounds__(256) void k_wconv(const float* __restrict__ W1,
        const float* __restrict__ W2, unsigned short* __restrict__ W1t,
        unsigned short* __restrict__ W2t) {
    int id = blockIdx.x * 256 + threadIdx.x;
    const int T1 = NLAYER * 4 * 256 * 32;      // 163840
    if (id < T1) {
        int k = id & 31, n = (id >> 5) & 255, kc = (id >> 13) & 3, l = id >> 15;
        W1t[id] = f2bf(W1[((size_t)(l * 128 + kc * 32 + k)) * 256 + n]);
    } else {
        int id2 = id - T1;
        if (id2 >= NLAYER * 8 * 128 * 32) return;
        int k = id2 & 31, n = (id2 >> 5) & 127, kc = (id2 >> 12) & 7, l = id2 >> 15;
        W2t[id2] = f2bf(W2[((size_t)(l * 256 + kc * 32 + k)) * 128 + n]);
    }
}

// ---------- CSR build (deg accumulated in rs[0..N-1]) ----------
__global__ __launch_bounds__(256) void k_deg(const int* __restrict__ ei, int* __restrict__ deg, int E) {
    int e = blockIdx.x * 256 + threadIdx.x;
    if (e < E) atomicAdd(&deg[ei[E + e]], 1);
}
__global__ __launch_bounds__(256) void k_bsum(const int* __restrict__ deg, int* __restrict__ bsum, int N) {
    __shared__ int red[256];
    int t = threadIdx.x, b = blockIdx.x;
    int i0 = b * 1024 + t * 4;
    int s = 0;
#pragma unroll
    for (int j = 0; j < 4; ++j) if (i0 + j < N) s += deg[i0 + j];
    red[t] = s; __syncthreads();
    for (int off = 128; off > 0; off >>= 1) {
        if (t < off) red[t] += red[t + off];
        __syncthreads();
    }
    if (t == 0) bsum[b] = red[0];
}
__global__ __launch_bounds__(256) void k_bscan(const int* __restrict__ bsum, int* __restrict__ boff, int nb) {
    __shared__ int ts[256];
    int t = threadIdx.x;
    int v = (t < nb) ? bsum[t] : 0;
    ts[t] = v; __syncthreads();
    for (int off = 1; off < 256; off <<= 1) {
        int u = (t >= off) ? ts[t - off] : 0;
        __syncthreads();
        ts[t] += u;
        __syncthreads();
    }
    if (t < nb) boff[t] = ts[t] - v;   // exclusive
}
// deg and rs alias the same array: each slot read-then-written by its owning thread
__global__ __launch_bounds__(256) void k_csr(const int* deg, const int* __restrict__ boff,
        int* rs, int N, int E) {
    __shared__ int ts[256];
    int t = threadIdx.x, b = blockIdx.x;
    int i0 = b * 1024 + t * 4;
    int d[4];
#pragma unroll
    for (int j = 0; j < 4; ++j) d[j] = (i0 + j < N) ? deg[i0 + j] : 0;
    int tsum = d[0] + d[1] + d[2] + d[3];
    ts[t] = tsum; __syncthreads();
    for (int off = 1; off < 256; off <<= 1) {
        int u = (t >= off) ? ts[t - off] : 0;
        __syncthreads();
        ts[t] += u;
        __syncthreads();
    }
    int base = boff[b] + ts[t] - tsum;
    int p = 0;
#pragma unroll
    for (int j = 0; j < 4; ++j) {
        int dj = d[j];
        if (i0 + j < N) rs[i0 + j] = base + p;
        p += dj;
    }
    if (b == 0 && t == 0) rs[N] = E;
}
// scatter: atomicAdd on rs (after this, rs[n] = end_n; start_n = n? rs[n-1] : 0)
__global__ __launch_bounds__(256) void k_scatter(const int* __restrict__ ei,
        const int* __restrict__ ea, int* __restrict__ rs, int2* __restrict__ epack, int E) {
    int e = blockIdx.x * 256 + threadIdx.x;
    if (e < E) {
        int pos = atomicAdd(&rs[ei[E + e]], 1);
        int code = ea[e * 3 + 0] | (ea[e * 3 + 1] << 8) | (ea[e * 3 + 2] << 16);
        epack[pos] = make_int2(ei[e], code);
    }
}

// ---------- fused: gather-aggregate + GIN combine + GEMM1 + BN1 stats ----------
__global__ __launch_bounds__(256) void k_fused1(
        const float* __restrict__ y2, const int* __restrict__ rs,
        const int2* __restrict__ epack, const float* __restrict__ bemb,
        const float* __restrict__ sumprev, const float* __restrict__ gprev,
        const float* __restrict__ bprev, const unsigned short* __restrict__ W1t,
        const float* __restrict__ bias, const float* __restrict__ epsv, int l,
        int mode, float invN, unsigned short* __restrict__ y1,
        float* __restrict__ stats, int N) {
    __shared__ unsigned int zt_u[64 * 16 * 4];   // 16KB z tile bf16, swizzled granules
    __shared__ uv4 wt[256 * 4];                  // 16KB W1 chunk
    __shared__ float scS[128], shS[128];
    int tid = threadIdx.x;
    int row0 = blockIdx.x * 64;
    if (mode && tid < 128) {
        float mu = sumprev[tid] * invN;
        float var = sumprev[128 + tid] * invN - mu * mu;
        float r = rsqrtf(var + 1e-5f);
        float sc = gprev[tid] * r;
        scS[tid] = sc; shS[tid] = bprev[tid] - mu * sc;
    }
    __syncthreads();
    float ep = 1.0f + epsv[l];
    int grp = tid >> 5, lane32 = tid & 31, c = lane32 << 2;
    float sc4[4] = {1.f, 1.f, 1.f, 1.f}, sh4[4] = {0.f, 0.f, 0.f, 0.f};
    if (mode) {
#pragma unroll
        for (int j = 0; j < 4; ++j) { sc4[j] = scS[c + j]; sh4[j] = shS[c + j]; }
    }
    for (int it = 0; it < 8; ++it) {
        int rloc = it * 8 + grp;
        int n = row0 + rloc;
        int p0 = (n == 0) ? 0 : rs[n - 1];
        int p1 = rs[n];
        float ag[4] = {0.f, 0.f, 0.f, 0.f};
        for (int p = p0; p < p1; ++p) {
            int2 ek = epack[p];
            int code = ek.y;
            float4 hv = *(const float4*)(y2 + (size_t)ek.x * DD + c);
            float hs[4] = {hv.x, hv.y, hv.z, hv.w};
            if (mode) {
#pragma unroll
                for (int j = 0; j < 4; ++j) hs[j] = fmaxf(hs[j] * sc4[j] + sh4[j], 0.f);
            }
            float4 v0 = *(const float4*)(bemb + (size_t)(code & 255) * DD + c);
            float4 v1 = *(const float4*)(bemb + (size_t)(6 + ((code >> 8) & 255)) * DD + c);
            float4 v2 = *(const float4*)(bemb + (size_t)(12 + (code >> 16)) * DD + c);
            ag[0] += fmaxf(hs[0] + v0.x + v1.x + v2.x, 0.f);
            ag[1] += fmaxf(hs[1] + v0.y + v1.y + v2.y, 0.f);
            ag[2] += fmaxf(hs[2] + v0.z + v1.z + v2.z, 0.f);
            ag[3] += fmaxf(hs[3] + v0.w + v1.w + v2.w, 0.f);
        }
        float4 sv = *(const float4*)(y2 + (size_t)n * DD + c);
        float hz[4] = {sv.x, sv.y, sv.z, sv.w};
        if (mode) {
#pragma unroll
            for (int j = 0; j < 4; ++j) hz[j] = fmaxf(hz[j] * sc4[j] + sh4[j], 0.f);
        }
        unsigned int w0 = (unsigned int)f2bf(ep * hz[0] + ag[0]) | ((unsigned int)f2bf(ep * hz[1] + ag[1]) << 16);
        unsigned int w1 = (unsigned int)f2bf(ep * hz[2] + ag[2]) | ((unsigned int)f2bf(ep * hz[3] + ag[3]) << 16);
        int gz = lane32 >> 1, half = lane32 & 1;
        ((uint2*)zt_u)[(rloc * 16 + (gz ^ (rloc & 15))) * 2 + half] = make_uint2(w0, w1);
    }

    int wave = tid >> 6, lane = tid & 63, lq = lane >> 4, lr = lane & 15;
    fv4 acc[4][4];
#pragma unroll
    for (int m = 0; m < 4; ++m)
#pragma unroll
        for (int nb = 0; nb < 4; ++nb) acc[m][nb] = (fv4){0.f, 0.f, 0.f, 0.f};

    const uv4* wsrc = (const uv4*)W1t + (size_t)l * 4096;
    const uv4* ztv = (const uv4*)zt_u;
    for (int kc = 0; kc < 4; ++kc) {
        __syncthreads();
#pragma unroll
        for (int i = 0; i < 4; ++i) {
            int g = i * 256 + tid;
            int wn = g >> 2, gw = g & 3;
            wt[wn * 4 + (gw ^ ((wn >> 1) & 3))] = wsrc[(size_t)kc * 1024 + g];
        }
        __syncthreads();
        bfv8 a[4], b[4];
#pragma unroll
        for (int m = 0; m < 4; ++m) {
            int row = m * 16 + lr;
            a[m] = __builtin_bit_cast(bfv8, ztv[row * 16 + ((kc * 4 + lq) ^ (row & 15))]);
        }
#pragma unroll
        for (int nb = 0; nb < 4; ++nb) {
            int col = wave * 64 + nb * 16 + lr;
            b[nb] = __builtin_bit_cast(bfv8, wt[col * 4 + (lq ^ ((col >> 1) & 3))]);
        }
#pragma unroll
        for (int m = 0; m < 4; ++m)
#pragma unroll
            for (int nb = 0; nb < 4; ++nb)
                acc[m][nb] = __builtin_amdgcn_mfma_f32_16x16x32_bf16(a[m], b[nb], acc[m][nb], 0, 0, 0);
    }

    float bv[4], s[4], q[4];
#pragma unroll
    for (int nb = 0; nb < 4; ++nb) {
        bv[nb] = bias[wave * 64 + nb * 16 + lr];
        s[nb] = 0.f; q[nb] = 0.f;
    }
#pragma unroll
    for (int m = 0; m < 4; ++m)
#pragma unroll
        for (int nb = 0; nb < 4; ++nb) {
            int col = wave * 64 + nb * 16 + lr;
#pragma unroll
            for (int r = 0; r < 4; ++r) {
                float v = acc[m][nb][r] + bv[nb];
                unsigned short ub = f2bf(v);
                float vr = bf2f(ub);
                int row = row0 + m * 16 + lq * 4 + r;
                y1[(size_t)row * HH + col] = ub;
                s[nb] += vr; q[nb] += vr * vr;
            }
        }
#pragma unroll
    for (int nb = 0; nb < 4; ++nb) {
        s[nb] += __shfl_xor(s[nb], 16); s[nb] += __shfl_xor(s[nb], 32);
        q[nb] += __shfl_xor(q[nb], 16); q[nb] += __shfl_xor(q[nb], 32);
    }
    if (lane < 16) {
#pragma unroll
        for (int nb = 0; nb < 4; ++nb) {
            int col = wave * 64 + nb * 16 + lr;
            atomicAdd(stats + col, s[nb]);
            atomicAdd(stats + HH + col, q[nb]);
        }
    }
}

// ---------- GEMM2 (MFMA): y2 = relu(bn1(y1)) @ W2 + b2 (+BN2 stats), in-block BN1 finalize ----------
__global__ __launch_bounds__(256) void k_gemm2(const unsigned short* __restrict__ y1,
        const unsigned short* __restrict__ W2t, const float* __restrict__ bias,
        const float* __restrict__ sum1, const float* __restrict__ bn1g,
        const float* __restrict__ bn1b, float invN,
        float* __restrict__ y2, float* __restrict__ stats2, int N) {
    __shared__ uv4 at[64 * 32];    // 32KB
    __shared__ uv4 wt[128 * 4];    // 8KB
    __shared__ float scS[256], shS[256];
    int tid = threadIdx.x;
    int row0 = blockIdx.x * 64;
    int wave = tid >> 6, lane = tid & 63, lq = lane >> 4, lr = lane & 15;
    {
        float mu = sum1[tid] * invN;
        float var = sum1[256 + tid] * invN - mu * mu;
        float r = rsqrtf(var + 1e-5f);
        float sc = bn1g[tid] * r;
        scS[tid] = sc; shS[tid] = bn1b[tid] - mu * sc;
    }
    __syncthreads();

#pragma unroll
    for (int i = 0; i < 8; ++i) {
        int idx = i * 256 + tid;
        int row = idx >> 5, g = idx & 31;
        uv4 raw = *((const uv4*)y1 + (size_t)(row0 + row) * 32 + g);
        uv4 p;
#pragma unroll
        for (int j = 0; j < 4; ++j) {
            int ch = g * 8 + 2 * j;
            float f0 = fmaxf(bf2f((unsigned short)(raw[j] & 0xFFFFu)) * scS[ch] + shS[ch], 0.f);
            float f1 = fmaxf(bf2f((unsigned short)(raw[j] >> 16)) * scS[ch + 1] + shS[ch + 1], 0.f);
            p[j] = (unsigned int)f2bf(f0) | ((unsigned int)f2bf(f1) << 16);
        }
        at[row * 32 + (g ^ (row & 15))] = p;
    }

    fv4 acc[4][2];
#pragma unroll
    for (int m = 0; m < 4; ++m) { acc[m][0] = (fv4){0.f,0.f,0.f,0.f}; acc[m][1] = (fv4){0.f,0.f,0.f,0.f}; }

    const uv4* wbase = (const uv4*)W2t;
    for (int kc = 0; kc < 8; ++kc) {
        __syncthreads();
#pragma unroll
        for (int i = 0; i < 2; ++i) {
            int g = i * 256 + tid;
            int wn = g >> 2, gw = g & 3;
            wt[wn * 4 + (gw ^ ((wn >> 1) & 3))] = wbase[(size_t)kc * 512 + g];
        }
        __syncthreads();
        bfv8 a[4], b[2];
#pragma unroll
        for (int m = 0; m < 4; ++m) {
            int row = m * 16 + lr;
            a[m] = __builtin_bit_cast(bfv8, at[row * 32 + ((kc * 4 + lq) ^ (row & 15))]);
        }
#pragma unroll
        for (int nb = 0; nb < 2; ++nb) {
            int col = wave * 32 + nb * 16 + lr;
            b[nb] = __builtin_bit_cast(bfv8, wt[col * 4 + (lq ^ ((col >> 1) & 3))]);
        }
#pragma unroll
        for (int m = 0; m < 4; ++m)
#pragma unroll
            for (int nb = 0; nb < 2; ++nb)
                acc[m][nb] = __builtin_amdgcn_mfma_f32_16x16x32_bf16(a[m], b[nb], acc[m][nb], 0, 0, 0);
    }

    float bv[2], s[2], q[2];
#pragma unroll
    for (int nb = 0; nb < 2; ++nb) {
        bv[nb] = bias[wave * 32 + nb * 16 + lr];
        s[nb] = 0.f; q[nb] = 0.f;
    }
#pragma unroll
    for (int m = 0; m < 4; ++m)
#pragma unroll
        for (int nb = 0; nb < 2; ++nb) {
            int col = wave * 32 + nb * 16 + lr;
#pragma unroll
            for (int r = 0; r < 4; ++r) {
                float v = acc[m][nb][r] + bv[nb];
                int row = row0 + m * 16 + lq * 4 + r;
                y2[(size_t)row * DD + col] = v;
                s[nb] += v; q[nb] += v * v;
            }
        }
#pragma unroll
    for (int nb = 0; nb < 2; ++nb) {
        s[nb] += __shfl_xor(s[nb], 16); s[nb] += __shfl_xor(s[nb], 32);
        q[nb] += __shfl_xor(q[nb], 16); q[nb] += __shfl_xor(q[nb], 32);
    }
    if (lane < 16) {
#pragma unroll
        for (int nb = 0; nb < 2; ++nb) {
            int col = wave * 32 + nb * 16 + lr;
            atomicAdd(stats2 + col, s[nb]);
            atomicAdd(stats2 + DD + col, q[nb]);
        }
    }
}

// ---------- final: out = relu(bn2(y2)) (f32), in-block BN finalize ----------
__global__ __launch_bounds__(256) void k_bnfinal(const float* __restrict__ y2,
        const float* __restrict__ sum2, const float* __restrict__ g,
        const float* __restrict__ b, float* __restrict__ out, float invN, int N) {
    __shared__ float scS[128], shS[128];
    int tid = threadIdx.x;
    if (tid < 128) {
        float mu = sum2[tid] * invN;
        float var = sum2[128 + tid] * invN - mu * mu;
        float r = rsqrtf(var + 1e-5f);
        float sc = g[tid] * r;
        scS[tid] = sc; shS[tid] = b[tid] - mu * sc;
    }
    __syncthreads();
    size_t base = ((size_t)blockIdx.x * 256 + tid) * 4;
    if (base >= (size_t)N * DD) return;
    int c = (int)(base & (DD - 1));
    float4 v = *(const float4*)(y2 + base);
    float4 o;
    o.x = fmaxf(v.x * scS[c] + shS[c], 0.f);
    o.y = fmaxf(v.y * scS[c + 1] + shS[c + 1], 0.f);
    o.z = fmaxf(v.z * scS[c + 2] + shS[c + 2], 0.f);
    o.w = fmaxf(v.w * scS[c + 3] + shS[c + 3], 0.f);
    *(float4*)(out + base) = o;
}

extern "C" void kernel_launch(void* const* d_in, const int* in_sizes, int n_in,
                              void* d_out, int out_size, void* d_ws, size_t ws_size,
                              hipStream_t stream) {
    const int* x = (const int*)d_in[0];
    const int* ei = (const int*)d_in[1];
    const int* ea = (const int*)d_in[2];
    const float* atom_emb = (const float*)d_in[3];
    const float* bond_emb = (const float*)d_in[4];
    const float* W1 = (const float*)d_in[5];
    const float* b1 = (const float*)d_in[6];
    const float* bn1_g = (const float*)d_in[7];
    const float* bn1_b = (const float*)d_in[8];
    const float* W2 = (const float*)d_in[9];
    const float* b2 = (const float*)d_in[10];
    const float* epsv = (const float*)d_in[11];
    const float* obn_g = (const float*)d_in[12];
    const float* obn_b = (const float*)d_in[13];
    int N = in_sizes[0] / NF_ATOM;   // 200000 (divisible by 64)
    int E = in_sizes[1] / 2;

    char* wsb = (char*)d_ws;
    float* y2 = (float*)wsb;                                           // N*128 f32 (state)
    unsigned short* y1b = (unsigned short*)(wsb + (size_t)N * 512);    // N*256 bf16
    int2* epack = (int2*)(wsb + (size_t)N * 1024);                     // E int2
    unsigned short* w1t = (unsigned short*)(wsb + (size_t)N * 1024 + (size_t)E * 8);
    unsigned short* w2t = w1t + 163840;
    int* rsarr = (int*)(w2t + 163840);                                 // N+1
    int* bsum = rsarr + (N + 1);                                       // 256
    int* boff = bsum + 256;                                            // 256
    float* st = (float*)(boff + 256);                                  // 5*768 f32
    float invN = 1.0f / (float)N;
    int nbk = (N + 1023) / 1024;

    k_wconv<<<1280, 256, 0, stream>>>(W1, W2, w1t, w2t);
    hipMemsetAsync(rsarr, 0, ((size_t)N + 1) * 4, stream);
    hipMemsetAsync(st, 0, NLAYER * 768 * sizeof(float), stream);
    k_deg<<<(E + 255) / 256, 256, 0, stream>>>(ei, rsarr, E);
    k_bsum<<<nbk, 256, 0, stream>>>(rsarr, bsum, N);
    k_bscan<<<1, 256, 0, stream>>>(bsum, boff, nbk);
    k_csr<<<nbk, 256, 0, stream>>>(rsarr, boff, rsarr, N, E);
    k_scatter<<<(E + 255) / 256, 256, 0, stream>>>(ei, ea, rsarr, epack, E);
    k_atom<<<(N * 32 + 255) / 256, 256, 0, stream>>>(x, atom_emb, y2, N);

    int gb = N / 64;
    for (int l = 0; l < NLAYER; ++l) {
        float* sum1 = st + l * 768;
        float* sum2 = st + l * 768 + 512;
        const float* sumprev = (l == 0) ? st : (st + (l - 1) * 768 + 512);
        const float* gprev = (l == 0) ? obn_g : (obn_g + (l - 1) * DD);
        const float* bprev = (l == 0) ? obn_b : (obn_b + (l - 1) * DD);
        k_fused1<<<gb, 256, 0, stream>>>(y2, rsarr, epack,
                bond_emb + (size_t)l * NF_BOND * 6 * DD, sumprev, gprev, bprev,
                w1t, b1 + l * HH, epsv, l, (l == 0) ? 0 : 1, invN, y1b, sum1, N);
        k_gemm2<<<gb, 256, 0, stream>>>(y1b, w2t + (size_t)l * 32768, b2 + l * DD,
                sum1, bn1_g + l * HH, bn1_b + l * HH, invN, y2, sum2, N);
    }
    k_bnfinal<<<(int)(((size_t)N * DD / 4 + 255) / 256), 256, 0, stream>>>(
            y2, st + 4 * 768 + 512, obn_g + 4 * DD, obn_b + 4 * DD, (float*)d_out, invN, N);
}

// Round 4
// 2388.308 us; speedup vs baseline: 1.0923x; 1.0923x over previous
//
#include <hip/hip_runtime.h>

#define NF_ATOM 9
#define NF_BOND 3
#define DD 128
#define HH 256
#define NLAYER 5

typedef float fv4 __attribute__((ext_vector_type(4)));
typedef __bf16 bfv8 __attribute__((ext_vector_type(8)));
typedef unsigned int uv4 __attribute__((ext_vector_type(4)));

__device__ inline unsigned short f2bf(float f) {
    unsigned int u = __builtin_bit_cast(unsigned int, f);
    u = u + 0x7FFFu + ((u >> 16) & 1u);
    return (unsigned short)(u >> 16);
}
__device__ inline float bf2f(unsigned short s) {
    unsigned int u = ((unsigned int)s) << 16;
    return __builtin_bit_cast(float, u);
}

// ---------- atom encoder: h0 (f32) into y2 buffer ----------
__global__ __launch_bounds__(256) void k_atom(const int* __restrict__ x,
        const float* __restrict__ emb, float* __restrict__ h, int N) {
    int gid = blockIdx.x * 256 + threadIdx.x;
    int n = gid >> 5;
    if (n >= N) return;
    int c = (gid & 31) << 2;
    const int* xr = x + n * NF_ATOM;
    float4 acc = make_float4(0.f, 0.f, 0.f, 0.f);
#pragma unroll
    for (int f = 0; f < NF_ATOM; ++f) {
        int idx = xr[f];
        float4 v = *(const float4*)(emb + ((size_t)(f * 120 + idx) * DD) + c);
        acc.x += v.x; acc.y += v.y; acc.z += v.z; acc.w += v.w;
    }
    *(float4*)(h + (size_t)n * DD + c) = acc;
}

// ---------- weight convert: f32 [K][N] -> bf16 chunk-major [l][kc][n][32k] ----------
__global__ __launch_bounds__(256) void k_wconv(const float* __restrict__ W1,
        const float* __restrict__ W2, unsigned short* __restrict__ W1t,
        unsigned short* __restrict__ W2t) {
    int id = blockIdx.x * 256 + threadIdx.x;
    const int T1 = NLAYER * 4 * 256 * 32;      // 163840
    if (id < T1) {
        int k = id & 31, n = (id >> 5) & 255, kc = (id >> 13) & 3, l = id >> 15;
        W1t[id] = f2bf(W1[((size_t)(l * 128 + kc * 32 + k)) * 256 + n]);
    } else {
        int id2 = id - T1;
        if (id2 >= NLAYER * 8 * 128 * 32) return;
        int k = id2 & 31, n = (id2 >> 5) & 127, kc = (id2 >> 12) & 7, l = id2 >> 15;
        W2t[id2] = f2bf(W2[((size_t)(l * 256 + kc * 32 + k)) * 128 + n]);
    }
}

// ---------- CSR build ----------
__global__ __launch_bounds__(256) void k_deg(const int* __restrict__ ei, int* __restrict__ deg, int E) {
    int e = blockIdx.x * 256 + threadIdx.x;
    if (e < E) atomicAdd(&deg[ei[E + e]], 1);
}
__global__ __launch_bounds__(256) void k_bsum(const int* __restrict__ deg, int* __restrict__ bsum, int N) {
    __shared__ int red[256];
    int t = threadIdx.x, b = blockIdx.x;
    int i0 = b * 1024 + t * 4;
    int s = 0;
#pragma unroll
    for (int j = 0; j < 4; ++j) if (i0 + j < N) s += deg[i0 + j];
    red[t] = s; __syncthreads();
    for (int off = 128; off > 0; off >>= 1) {
        if (t < off) red[t] += red[t + off];
        __syncthreads();
    }
    if (t == 0) bsum[b] = red[0];
}
__global__ __launch_bounds__(256) void k_bscan(const int* __restrict__ bsum, int* __restrict__ boff, int nb) {
    __shared__ int ts[256];
    int t = threadIdx.x;
    int v = (t < nb) ? bsum[t] : 0;
    ts[t] = v; __syncthreads();
    for (int off = 1; off < 256; off <<= 1) {
        int u = (t >= off) ? ts[t - off] : 0;
        __syncthreads();
        ts[t] += u;
        __syncthreads();
    }
    if (t < nb) boff[t] = ts[t] - v;   // exclusive
}
__global__ __launch_bounds__(256) void k_csr(const int* deg, const int* __restrict__ boff,
        int* rs, int N, int E) {
    __shared__ int ts[256];
    int t = threadIdx.x, b = blockIdx.x;
    int i0 = b * 1024 + t * 4;
    int d[4];
#pragma unroll
    for (int j = 0; j < 4; ++j) d[j] = (i0 + j < N) ? deg[i0 + j] : 0;
    int tsum = d[0] + d[1] + d[2] + d[3];
    ts[t] = tsum; __syncthreads();
    for (int off = 1; off < 256; off <<= 1) {
        int u = (t >= off) ? ts[t - off] : 0;
        __syncthreads();
        ts[t] += u;
        __syncthreads();
    }
    int base = boff[b] + ts[t] - tsum;
    int p = 0;
#pragma unroll
    for (int j = 0; j < 4; ++j) {
        int dj = d[j];
        if (i0 + j < N) rs[i0 + j] = base + p;
        p += dj;
    }
    if (b == 0 && t == 0) rs[N] = E;
}
// after scatter: rs[n] = end_n ; start_n = n ? rs[n-1] : 0
__global__ __launch_bounds__(256) void k_scatter(const int* __restrict__ ei,
        const int* __restrict__ ea, int* __restrict__ rs, int2* __restrict__ epack, int E) {
    int e = blockIdx.x * 256 + threadIdx.x;
    if (e < E) {
        int pos = atomicAdd(&rs[ei[E + e]], 1);
        int code = ea[e * 3 + 0] | (ea[e * 3 + 1] << 8) | (ea[e * 3 + 2] << 16);
        epack[pos] = make_int2(ei[e], code);
    }
}

// ---------- zbuild: z = (1+eps)*hn + sum_e relu(hn_src + bond), hn = relu(bn_prev(y2)) ----------
// 32 lanes per node, no LDS -> high occupancy for the latency-bound gather.
__global__ __launch_bounds__(256) void k_zbuild(const float* __restrict__ y2,
        const int* __restrict__ rs, const int2* __restrict__ epack,
        const float* __restrict__ bemb, const float* __restrict__ sumprev,
        const float* __restrict__ gprev, const float* __restrict__ bprev,
        const float* __restrict__ epsv, int l, int mode, float invN,
        unsigned short* __restrict__ z, int N) {
    int gid = blockIdx.x * 256 + threadIdx.x;
    int n = gid >> 5;
    if (n >= N) return;
    int c = (gid & 31) << 2;
    float sc4[4] = {1.f, 1.f, 1.f, 1.f}, sh4[4] = {0.f, 0.f, 0.f, 0.f};
    if (mode) {
#pragma unroll
        for (int j = 0; j < 4; ++j) {
            float mu = sumprev[c + j] * invN;
            float var = sumprev[DD + c + j] * invN - mu * mu;
            float r = rsqrtf(var + 1e-5f);
            float sc = gprev[c + j] * r;
            sc4[j] = sc; sh4[j] = bprev[c + j] - mu * sc;
        }
    }
    int p0 = (n == 0) ? 0 : rs[n - 1];
    int p1 = rs[n];
    float ag[4] = {0.f, 0.f, 0.f, 0.f};
    for (int p = p0; p < p1; ++p) {
        int2 ek = epack[p];
        int code = ek.y;
        float4 hv = *(const float4*)(y2 + (size_t)ek.x * DD + c);
        float hs[4] = {hv.x, hv.y, hv.z, hv.w};
        if (mode) {
#pragma unroll
            for (int j = 0; j < 4; ++j) hs[j] = fmaxf(hs[j] * sc4[j] + sh4[j], 0.f);
        }
        float4 v0 = *(const float4*)(bemb + (size_t)(code & 255) * DD + c);
        float4 v1 = *(const float4*)(bemb + (size_t)(6 + ((code >> 8) & 255)) * DD + c);
        float4 v2 = *(const float4*)(bemb + (size_t)(12 + (code >> 16)) * DD + c);
        ag[0] += fmaxf(hs[0] + v0.x + v1.x + v2.x, 0.f);
        ag[1] += fmaxf(hs[1] + v0.y + v1.y + v2.y, 0.f);
        ag[2] += fmaxf(hs[2] + v0.z + v1.z + v2.z, 0.f);
        ag[3] += fmaxf(hs[3] + v0.w + v1.w + v2.w, 0.f);
    }
    float ep = 1.0f + epsv[l];
    float4 sv = *(const float4*)(y2 + (size_t)n * DD + c);
    float hz[4] = {sv.x, sv.y, sv.z, sv.w};
    if (mode) {
#pragma unroll
        for (int j = 0; j < 4; ++j) hz[j] = fmaxf(hz[j] * sc4[j] + sh4[j], 0.f);
    }
    ushort4 o;
    o.x = f2bf(ep * hz[0] + ag[0]);
    o.y = f2bf(ep * hz[1] + ag[1]);
    o.z = f2bf(ep * hz[2] + ag[2]);
    o.w = f2bf(ep * hz[3] + ag[3]);
    *(ushort4*)(z + (size_t)n * DD + c) = o;
}

// ---------- GEMM1 (MFMA, no LDS): y1 = z @ W1 + b1, BN1 stats ----------
__global__ __launch_bounds__(256) void k_gemm1(const unsigned short* __restrict__ z,
        const unsigned short* __restrict__ W1l, const float* __restrict__ bias,
        unsigned short* __restrict__ y1, float* __restrict__ stats, int N) {
    int tid = threadIdx.x;
    int row0 = blockIdx.x * 64;
    int wave = tid >> 6, lane = tid & 63, lq = lane >> 4, lr = lane & 15;
    fv4 acc[4][4];
#pragma unroll
    for (int m = 0; m < 4; ++m)
#pragma unroll
        for (int nb = 0; nb < 4; ++nb) acc[m][nb] = (fv4){0.f, 0.f, 0.f, 0.f};
    const unsigned short* zb = z + (size_t)row0 * DD;
#pragma unroll
    for (int kc = 0; kc < 4; ++kc) {
        bfv8 a[4], b[4];
#pragma unroll
        for (int m = 0; m < 4; ++m)
            a[m] = *(const bfv8*)(zb + (m * 16 + lr) * DD + kc * 32 + lq * 8);
#pragma unroll
        for (int nb = 0; nb < 4; ++nb) {
            int col = wave * 64 + nb * 16 + lr;
            b[nb] = *(const bfv8*)(W1l + ((size_t)(kc * 256 + col)) * 32 + lq * 8);
        }
#pragma unroll
        for (int m = 0; m < 4; ++m)
#pragma unroll
            for (int nb = 0; nb < 4; ++nb)
                acc[m][nb] = __builtin_amdgcn_mfma_f32_16x16x32_bf16(a[m], b[nb], acc[m][nb], 0, 0, 0);
    }
    float bv[4], s[4], q[4];
#pragma unroll
    for (int nb = 0; nb < 4; ++nb) {
        bv[nb] = bias[wave * 64 + nb * 16 + lr];
        s[nb] = 0.f; q[nb] = 0.f;
    }
#pragma unroll
    for (int m = 0; m < 4; ++m)
#pragma unroll
        for (int nb = 0; nb < 4; ++nb) {
            int col = wave * 64 + nb * 16 + lr;
#pragma unroll
            for (int r = 0; r < 4; ++r) {
                float v = acc[m][nb][r] + bv[nb];
                unsigned short ub = f2bf(v);
                float vr = bf2f(ub);
                int row = row0 + m * 16 + lq * 4 + r;
                y1[(size_t)row * HH + col] = ub;
                s[nb] += vr; q[nb] += vr * vr;
            }
        }
#pragma unroll
    for (int nb = 0; nb < 4; ++nb) {
        s[nb] += __shfl_xor(s[nb], 16); s[nb] += __shfl_xor(s[nb], 32);
        q[nb] += __shfl_xor(q[nb], 16); q[nb] += __shfl_xor(q[nb], 32);
    }
    if (lane < 16) {
#pragma unroll
        for (int nb = 0; nb < 4; ++nb) {
            int col = wave * 64 + nb * 16 + lr;
            atomicAdd(stats + col, s[nb]);
            atomicAdd(stats + HH + col, q[nb]);
        }
    }
}

// ---------- GEMM2 (MFMA): y2 = relu(bn1(y1)) @ W2 + b2, BN2 stats; A in LDS, W2 global ----------
__global__ __launch_bounds__(256) void k_gemm2(const unsigned short* __restrict__ y1,
        const unsigned short* __restrict__ W2l, const float* __restrict__ bias,
        const float* __restrict__ sum1, const float* __restrict__ bn1g,
        const float* __restrict__ bn1b, float invN,
        float* __restrict__ y2, float* __restrict__ stats2, int N) {
    __shared__ uv4 at[64 * 32];    // 32KB
    __shared__ float scS[256], shS[256];
    int tid = threadIdx.x;
    int row0 = blockIdx.x * 64;
    int wave = tid >> 6, lane = tid & 63, lq = lane >> 4, lr = lane & 15;
    {
        float mu = sum1[tid] * invN;
        float var = sum1[256 + tid] * invN - mu * mu;
        float r = rsqrtf(var + 1e-5f);
        float sc = bn1g[tid] * r;
        scS[tid] = sc; shS[tid] = bn1b[tid] - mu * sc;
    }
    __syncthreads();
#pragma unroll
    for (int i = 0; i < 8; ++i) {
        int idx = i * 256 + tid;
        int row = idx >> 5, g = idx & 31;
        uv4 raw = *((const uv4*)y1 + (size_t)(row0 + row) * 32 + g);
        uv4 p;
#pragma unroll
        for (int j = 0; j < 4; ++j) {
            int ch = g * 8 + 2 * j;
            float f0 = fmaxf(bf2f((unsigned short)(raw[j] & 0xFFFFu)) * scS[ch] + shS[ch], 0.f);
            float f1 = fmaxf(bf2f((unsigned short)(raw[j] >> 16)) * scS[ch + 1] + shS[ch + 1], 0.f);
            p[j] = (unsigned int)f2bf(f0) | ((unsigned int)f2bf(f1) << 16);
        }
        at[row * 32 + (g ^ (row & 15))] = p;
    }
    __syncthreads();

    fv4 acc[4][2];
#pragma unroll
    for (int m = 0; m < 4; ++m) { acc[m][0] = (fv4){0.f,0.f,0.f,0.f}; acc[m][1] = (fv4){0.f,0.f,0.f,0.f}; }
#pragma unroll
    for (int kc = 0; kc < 8; ++kc) {
        bfv8 a[4], b[2];
#pragma unroll
        for (int m = 0; m < 4; ++m) {
            int row = m * 16 + lr;
            a[m] = __builtin_bit_cast(bfv8, at[row * 32 + ((kc * 4 + lq) ^ (row & 15))]);
        }
#pragma unroll
        for (int nb = 0; nb < 2; ++nb) {
            int col = wave * 32 + nb * 16 + lr;
            b[nb] = *(const bfv8*)(W2l + ((size_t)(kc * 128 + col)) * 32 + lq * 8);
        }
#pragma unroll
        for (int m = 0; m < 4; ++m)
#pragma unroll
            for (int nb = 0; nb < 2; ++nb)
                acc[m][nb] = __builtin_amdgcn_mfma_f32_16x16x32_bf16(a[m], b[nb], acc[m][nb], 0, 0, 0);
    }

    float bv[2], s[2], q[2];
#pragma unroll
    for (int nb = 0; nb < 2; ++nb) {
        bv[nb] = bias[wave * 32 + nb * 16 + lr];
        s[nb] = 0.f; q[nb] = 0.f;
    }
#pragma unroll
    for (int m = 0; m < 4; ++m)
#pragma unroll
        for (int nb = 0; nb < 2; ++nb) {
            int col = wave * 32 + nb * 16 + lr;
#pragma unroll
            for (int r = 0; r < 4; ++r) {
                float v = acc[m][nb][r] + bv[nb];
                int row = row0 + m * 16 + lq * 4 + r;
                y2[(size_t)row * DD + col] = v;
                s[nb] += v; q[nb] += v * v;
            }
        }
#pragma unroll
    for (int nb = 0; nb < 2; ++nb) {
        s[nb] += __shfl_xor(s[nb], 16); s[nb] += __shfl_xor(s[nb], 32);
        q[nb] += __shfl_xor(q[nb], 16); q[nb] += __shfl_xor(q[nb], 32);
    }
    if (lane < 16) {
#pragma unroll
        for (int nb = 0; nb < 2; ++nb) {
            int col = wave * 32 + nb * 16 + lr;
            atomicAdd(stats2 + col, s[nb]);
            atomicAdd(stats2 + DD + col, q[nb]);
        }
    }
}

// ---------- final: out = relu(bn2(y2)) ----------
__global__ __launch_bounds__(256) void k_bnfinal(const float* __restrict__ y2,
        const float* __restrict__ sum2, const float* __restrict__ g,
        const float* __restrict__ b, float* __restrict__ out, float invN, int N) {
    __shared__ float scS[128], shS[128];
    int tid = threadIdx.x;
    if (tid < 128) {
        float mu = sum2[tid] * invN;
        float var = sum2[128 + tid] * invN - mu * mu;
        float r = rsqrtf(var + 1e-5f);
        float sc = g[tid] * r;
        scS[tid] = sc; shS[tid] = b[tid] - mu * sc;
    }
    __syncthreads();
    size_t base = ((size_t)blockIdx.x * 256 + tid) * 4;
    if (base >= (size_t)N * DD) return;
    int c = (int)(base & (DD - 1));
    float4 v = *(const float4*)(y2 + base);
    float4 o;
    o.x = fmaxf(v.x * scS[c] + shS[c], 0.f);
    o.y = fmaxf(v.y * scS[c + 1] + shS[c + 1], 0.f);
    o.z = fmaxf(v.z * scS[c + 2] + shS[c + 2], 0.f);
    o.w = fmaxf(v.w * scS[c + 3] + shS[c + 3], 0.f);
    *(float4*)(out + base) = o;
}

extern "C" void kernel_launch(void* const* d_in, const int* in_sizes, int n_in,
                              void* d_out, int out_size, void* d_ws, size_t ws_size,
                              hipStream_t stream) {
    const int* x = (const int*)d_in[0];
    const int* ei = (const int*)d_in[1];
    const int* ea = (const int*)d_in[2];
    const float* atom_emb = (const float*)d_in[3];
    const float* bond_emb = (const float*)d_in[4];
    const float* W1 = (const float*)d_in[5];
    const float* b1 = (const float*)d_in[6];
    const float* bn1_g = (const float*)d_in[7];
    const float* bn1_b = (const float*)d_in[8];
    const float* W2 = (const float*)d_in[9];
    const float* b2 = (const float*)d_in[10];
    const float* epsv = (const float*)d_in[11];
    const float* obn_g = (const float*)d_in[12];
    const float* obn_b = (const float*)d_in[13];
    int N = in_sizes[0] / NF_ATOM;   // 200000 (divisible by 64)
    int E = in_sizes[1] / 2;

    char* wsb = (char*)d_ws;
    float* y2 = (float*)wsb;                                           // N*128 f32 (state)
    unsigned short* zb = (unsigned short*)(wsb + (size_t)N * 512);     // N*128 bf16
    unsigned short* y1b = (unsigned short*)(wsb + (size_t)N * 768);    // N*256 bf16
    int2* epack = (int2*)(wsb + (size_t)N * 1280);                     // E int2
    unsigned short* w1t = (unsigned short*)(wsb + (size_t)N * 1280 + (size_t)E * 8);
    unsigned short* w2t = w1t + 163840;
    int* rsarr = (int*)(w2t + 163840);                                 // N+1
    int* bsum = rsarr + (N + 1);                                       // 256
    int* boff = bsum + 256;                                            // 256
    float* st = (float*)(boff + 256);                                  // 5*768 f32
    float invN = 1.0f / (float)N;
    int nbk = (N + 1023) / 1024;

    k_wconv<<<1280, 256, 0, stream>>>(W1, W2, w1t, w2t);
    hipMemsetAsync(rsarr, 0, ((size_t)N + 1) * 4, stream);
    hipMemsetAsync(st, 0, NLAYER * 768 * sizeof(float), stream);
    k_deg<<<(E + 255) / 256, 256, 0, stream>>>(ei, rsarr, E);
    k_bsum<<<nbk, 256, 0, stream>>>(rsarr, bsum, N);
    k_bscan<<<1, 256, 0, stream>>>(bsum, boff, nbk);
    k_csr<<<nbk, 256, 0, stream>>>(rsarr, boff, rsarr, N, E);
    k_scatter<<<(E + 255) / 256, 256, 0, stream>>>(ei, ea, rsarr, epack, E);
    k_atom<<<(N * 32 + 255) / 256, 256, 0, stream>>>(x, atom_emb, y2, N);

    int gb = N / 64;
    for (int l = 0; l < NLAYER; ++l) {
        float* sum1 = st + l * 768;
        float* sum2 = st + l * 768 + 512;
        const float* sumprev = (l == 0) ? st : (st + (l - 1) * 768 + 512);
        const float* gprev = (l == 0) ? obn_g : (obn_g + (l - 1) * DD);
        const float* bprev = (l == 0) ? obn_b : (obn_b + (l - 1) * DD);
        k_zbuild<<<(N * 32 + 255) / 256, 256, 0, stream>>>(y2, rsarr, epack,
                bond_emb + (size_t)l * NF_BOND * 6 * DD, sumprev, gprev, bprev,
                epsv, l, (l == 0) ? 0 : 1, invN, zb, N);
        k_gemm1<<<gb, 256, 0, stream>>>(zb, w1t + (size_t)l * 32768,
                b1 + l * HH, y1b, sum1, N);
        k_gemm2<<<gb, 256, 0, stream>>>(y1b, w2t + (size_t)l * 32768, b2 + l * DD,
                sum1, bn1_g + l * HH, bn1_b + l * HH, invN, y2, sum2, N);
    }
    k_bnfinal<<<(int)(((size_t)N * DD / 4 + 255) / 256), 256, 0, stream>>>(
            y2, st + 4 * 768 + 512, obn_g + 4 * DD, obn_b + 4 * DD, (float*)d_out, invN, N);
}